// Round 12
// baseline (604.824 us; speedup 1.0000x reference)
//
#include <hip/hip_runtime.h>
#include <hip/hip_bf16.h>
#include <math.h>

#define BB 2
#define CIN 3
#define IMGS 256
#define PS 16
#define GG 16
#define NN 256
#define DIM 768
#define NH 12
#define NL 8
#define FFD 2048
#define LNEPS 1e-5f

typedef __attribute__((ext_vector_type(8))) short bf16x8;
typedef __attribute__((ext_vector_type(8))) unsigned short u16x8;
typedef __attribute__((ext_vector_type(4))) unsigned short u16x4;
typedef __attribute__((ext_vector_type(4))) float f32x4;

// ---- gemm mode flags ----
#define MB     1    // add bias[col]
#define MB2    2    // bias * 2 (implies bias)
#define MPOS   4    // add pos_embed[(row%256)*N + col]
#define MRELU  8
#define MRES   16   // C += result (residual, fp32)
#define MOBF16 32   // write bf16 to C16 instead of fp32 C
#define MAS2   64   // A = two fp32 arrays, summed + converted during staging
#define MLNA   256  // A = fp32 h + layernorm; stats reduced from pstat partials
#define MAIM2  512  // A = raw image x, im2col during staging (fp32)
#define MSTATP 1024 // epilogue: write per-wave (sum,sumsq) row partials (BN=32,N=768)

#define IPW_N  1769472
#define OW_N   589824
#define F1_N   1572864
#define F2_N   1572864
#define WCT_N  1769472
#define PW_N   589824

__device__ inline unsigned short bc(float f) {
    return __builtin_bit_cast(unsigned short, __float2bfloat16(f));
}
__device__ inline float fbc(unsigned short u) {
    unsigned int x = ((unsigned int)u) << 16;
    return __builtin_bit_cast(float, x);
}

__device__ inline void gload16(const unsigned short* g, unsigned short* l) {
    __builtin_amdgcn_global_load_lds((const __attribute__((address_space(1))) void*)g,
                                     (__attribute__((address_space(3))) void*)l, 16, 0, 0);
}

// C[M,N] = A[M,K] * B[N,K]^T + epilogue. Tile BM=32 x BN (32 or 64), 4 waves
// (2x2; each wave 16 x 16*NI). B always bf16 via global_load_lds; A bf16
// gload_lds unless reg-staged (MAS2/MLNA/MAIM2). 1-D grid, m204 chunked XCD
// swizzle, bx-major ids. LDS linear dest; XOR swizzle both sides (rule #21).
// MLNA: prologue reduces 48 pstat partials/row (12KB L2) -> sstat. MSTATP:
// epilogue writes per-wave row partials (no atomics; round-5/7 lessons).
template<int MODE, int BN>
__global__ __launch_bounds__(256) void gemm_bf16(
    const void* __restrict__ Av, const void* __restrict__ A2v,
    const unsigned short* __restrict__ B16,
    const float* __restrict__ bias, const float* __restrict__ pos,
    const float2* __restrict__ pstat,
    const float* __restrict__ lng, const float* __restrict__ lnb,
    float2* __restrict__ pstatOut,
    float* __restrict__ C, unsigned short* __restrict__ C16,
    int M, int N, int K, int zdiv,
    long long sAo, long long sBi, long long sCo, long long sCi)
{
    constexpr int NI = BN / 32;
    int z = blockIdx.y;
    int zo = z / zdiv, zi = z % zdiv;
    const unsigned short* A16 = (const unsigned short*)Av + (size_t)zo * sAo;
    const float* Af  = (const float*)Av  + (size_t)zo * sAo;
    const float* Af2 = (const float*)A2v + (size_t)zo * sAo;
    B16 += (size_t)zi * sBi;
    long long coff = (long long)zo * sCo + (long long)zi * sCi;

    int NBY = M >> 5;
    int nbysh = 31 - __builtin_clz(NBY);
    int id = blockIdx.x;
    int qch = gridDim.x >> 3;
    int wgid = (id & 7) * qch + (id >> 3);
    int bx = wgid >> nbysh, by = wgid & (NBY - 1);
    int bm = by * 32, bn = bx * BN;

    __shared__ __align__(16) unsigned short As[2][2048], Bs[2][BN * 64];
    __shared__ float2 sstat[32];
    int tid = threadIdx.x;
    int lane = tid & 63, wave = tid >> 6;
    int wr = wave >> 1, wc = wave & 1;
    int sA = tid;
    int srowA = sA >> 3, schkA = (sA & 7) ^ (srowA & 7);

    if constexpr (MODE & MLNA) {
        // reduce 48 partials per row (8 thr/row, 6 float2 each, coalesced)
        int row = tid >> 3, j = tid & 7;
        const float2* pr = pstat + (size_t)(bm + row) * 48 + j * 6;
        float s = 0.f, s2 = 0.f;
        #pragma unroll
        for (int k = 0; k < 6; ++k) { float2 v = pr[k]; s += v.x; s2 += v.y; }
        #pragma unroll
        for (int m2 = 1; m2 < 8; m2 <<= 1) {
            s  += __shfl_xor(s, m2);
            s2 += __shfl_xor(s2, m2);
        }
        if (j == 0) {
            float mean = s * (1.f / DIM);
            float var = s2 * (1.f / DIM) - mean * mean;
            sstat[row] = make_float2(mean, rsqrtf(var + LNEPS));
        }
        __syncthreads();
    }

    f32x4 acc[NI] = {};
    f32x4 rA0, rA1, rA20, rA21, gv0, gv1, bv0, bv1;
    float2 strow;

    auto gstageA = [&](int b, int kt) {
        gload16(A16 + (size_t)(bm + srowA) * K + kt * 64 + schkA * 8, &As[b][sA * 8]);
    };
    auto gstageB = [&](int b, int kt) {
        #pragma unroll
        for (int i = 0; i < NI; ++i) {
            int s = tid + i * 256;
            int row = s >> 3, chk = (s & 7) ^ (row & 7);
            gload16(B16 + (size_t)(bn + row) * K + kt * 64 + chk * 8, &Bs[b][s * 8]);
        }
    };
    auto ldA = [&](int kt) {
        int k0 = kt * 64 + schkA * 8;
        if constexpr (MODE & MAIM2) {
            int m = bm + srowA;
            int bq = m >> 8, n = m & 255, gy = n >> 4, gx = n & 15;
            int c = k0 >> 8, rem = k0 & 255, py = rem >> 4, px = rem & 15;
            const float* src = Af + (((size_t)(bq * CIN + c) * IMGS + gy * PS + py) << 8)
                             + gx * PS + px;
            rA0 = *(const f32x4*)(src);
            rA1 = *(const f32x4*)(src + 4);
        } else {
            size_t off = (size_t)(bm + srowA) * K + k0;
            rA0 = *(const f32x4*)(Af + off);
            rA1 = *(const f32x4*)(Af + off + 4);
            if constexpr (MODE & MAS2) {
                rA20 = *(const f32x4*)(Af2 + off);
                rA21 = *(const f32x4*)(Af2 + off + 4);
            }
            if constexpr (MODE & MLNA) {
                strow = sstat[srowA];
                gv0 = *(const f32x4*)(lng + k0); gv1 = *(const f32x4*)(lng + k0 + 4);
                bv0 = *(const f32x4*)(lnb + k0); bv1 = *(const f32x4*)(lnb + k0 + 4);
            }
        }
    };
    auto wrA = [&](int b) {
        bf16x8 v;
        #pragma unroll
        for (int j = 0; j < 4; ++j) {
            float x0 = rA0[j], x1 = rA1[j];
            if constexpr (MODE & MAS2) { x0 += rA20[j]; x1 += rA21[j]; }
            if constexpr (MODE & MLNA) {
                x0 = (x0 - strow.x) * strow.y * gv0[j] + bv0[j];
                x1 = (x1 - strow.x) * strow.y * gv1[j] + bv1[j];
            }
            v[j] = (short)bc(x0); v[4 + j] = (short)bc(x1);
        }
        *(bf16x8*)(&As[b][sA * 8]) = v;
    };
    constexpr bool regA = (MODE & (MAS2 | MLNA | MAIM2)) != 0;
    auto compute = [&](int b) {
        const unsigned short* Ab = As[b];
        const unsigned short* Bb = Bs[b];
        int rl = lane & 15, kh = lane >> 4;
        #pragma unroll
        for (int ks = 0; ks < 2; ++ks) {
            int kc = ks * 4 + kh;
            int ar = 16 * wr + rl;
            bf16x8 af = *(const bf16x8*)(Ab + ar * 64 + (kc ^ (ar & 7)) * 8);
            #pragma unroll
            for (int ni = 0; ni < NI; ++ni) {
                int br = 16 * NI * wc + 16 * ni + rl;
                bf16x8 bf = *(const bf16x8*)(Bb + br * 64 + (kc ^ (br & 7)) * 8);
                acc[ni] = __builtin_amdgcn_mfma_f32_16x16x32_bf16(af, bf, acc[ni], 0, 0, 0);
            }
        }
    };

    int nt = K >> 6;
    if constexpr (!regA) gstageA(0, 0); else { ldA(0); wrA(0); }
    gstageB(0, 0);
    __syncthreads();
    int buf = 0;
    for (int t = 0; t < nt; ++t) {
        if (t + 1 < nt) {
            if constexpr (!regA) gstageA(buf ^ 1, t + 1); else ldA(t + 1);
            gstageB(buf ^ 1, t + 1);
        }
        compute(buf);
        if (t + 1 < nt) {
            if constexpr (regA) wrA(buf ^ 1);
        }
        __syncthreads();
        buf ^= 1;
    }

    float vfin[4];
    #pragma unroll
    for (int ni = 0; ni < NI; ++ni) {
        #pragma unroll
        for (int r = 0; r < 4; ++r) {
            int row = bm + 16 * wr + (lane >> 4) * 4 + r;
            int col = bn + 16 * NI * wc + 16 * ni + (lane & 15);
            float v = acc[ni][r];
            if (MODE & (MB | MB2)) v += bias[col] * ((MODE & MB2) ? 2.f : 1.f);
            if (MODE & MPOS) v += pos[(size_t)(row & (NN - 1)) * N + col];
            if (MODE & MRELU) v = fmaxf(v, 0.f);
            long long ci = coff + (long long)row * N + col;
            if (MODE & MOBF16) { C16[ci] = bc(v); }
            else if (MODE & MRES) { v += C[ci]; C[ci] = v; }
            else { C[ci] = v; }
            if (ni == 0) vfin[r] = v;
        }
    }
    if constexpr (MODE & MSTATP) {
        // per-wave 16-col partials; lane&15==0 writes 4 rows (8B each, no atomics)
        #pragma unroll
        for (int r = 0; r < 4; ++r) {
            float s = vfin[r], s2 = vfin[r] * vfin[r];
            #pragma unroll
            for (int m2 = 1; m2 < 16; m2 <<= 1) {
                s  += __shfl_xor(s, m2);
                s2 += __shfl_xor(s2, m2);
            }
            if ((lane & 15) == 0) {
                int row = bm + 16 * wr + (lane >> 4) * 4 + r;
                pstatOut[(size_t)row * 48 + bx * 2 + wc] = make_float2(s, s2);
            }
        }
    }
}

// Wct16[dydx][oc][c] = bf16(conv1_w[oc][c][dy][dx]); one block per oc,
// coalesced 27KB read into LDS, coalesced bf16 writes.
__global__ __launch_bounds__(256) void wct_kernel(const float* __restrict__ conv1_w,
                                                  unsigned short* __restrict__ Wct16)
{
    int oc = blockIdx.x;
    int tid = threadIdx.x;
    __shared__ float w[6912];
    const float* src = conv1_w + (size_t)oc * 6912;
    #pragma unroll
    for (int k = 0; k < 27; ++k) w[tid + k * 256] = src[tid + k * 256];
    __syncthreads();
    #pragma unroll
    for (int dydx = 0; dydx < 9; ++dydx) {
        #pragma unroll
        for (int k = 0; k < 3; ++k) {
            int c = tid + k * 256;
            Wct16[(size_t)dydx * 196608 + oc * 768 + c] = bc(w[c * 9 + dydx]);
        }
    }
}

// Pure streaming fp32->bf16, 5 contiguous segments by blockIdx.y.
// Lane-contiguous pattern (m13-style): each block owns 4096 floats; thread t
// handles 4 chunks at t*4 + k*1024 — every load is 16B/lane contiguous,
// every store 8B/lane contiguous. All segment sizes divide 4096.
__global__ __launch_bounds__(256) void cvtflat_kernel(
    const float* __restrict__ ipw, const float* __restrict__ ow,
    const float* __restrict__ f1, const float* __restrict__ f2,
    const float* __restrict__ pw,
    unsigned short* __restrict__ d_ipw, unsigned short* __restrict__ d_ow,
    unsigned short* __restrict__ d_f1, unsigned short* __restrict__ d_f2,
    unsigned short* __restrict__ d_pw)
{
    int y = blockIdx.y;
    const float* src; unsigned short* dst; int n;
    if (y == 0)      { src = ipw; dst = d_ipw; n = 8 * IPW_N; }
    else if (y == 1) { src = ow;  dst = d_ow;  n = 8 * OW_N; }
    else if (y == 2) { src = f1;  dst = d_f1;  n = 8 * F1_N; }
    else if (y == 3) { src = f2;  dst = d_f2;  n = 8 * F2_N; }
    else             { src = pw;  dst = d_pw;  n = PW_N; }
    int base = blockIdx.x * 4096;
    if (base >= n) return;
    int t4 = threadIdx.x * 4;
    #pragma unroll
    for (int k = 0; k < 4; ++k) {
        int off = base + k * 1024 + t4;
        f32x4 v = *(const f32x4*)(src + off);
        u16x4 o;
        o[0] = bc(v[0]); o[1] = bc(v[1]); o[2] = bc(v[2]); o[3] = bc(v[3]);
        *(u16x4*)(dst + off) = o;
    }
}

// grid (B*G, 2 types, 12 heads). amh slice: [type][b][n][h] (per layer)
__global__ __launch_bounds__(256) void attn_kernel(
    const float* __restrict__ qkv, float* __restrict__ orow,
    float* __restrict__ ocol, float* __restrict__ amh)
{
    int b = blockIdx.x >> 4, g = blockIdx.x & 15;
    int type = blockIdx.y;
    int hh = blockIdx.z;
    int tid = threadIdx.x;
    __shared__ float qs[16][68], ks[16][68], vs[16][68], as_[16][17];
    {
        int sr = tid >> 4, dq = tid & 15;
        int n = (type == 0) ? (sr * GG + g) : (g * GG + sr);
        const float* base = qkv + (size_t)(b * NN + n) * (3 * DIM) + hh * 64 + dq * 4;
        float4 qv = *(const float4*)(base);
        float4 kv = *(const float4*)(base + DIM);
        float4 vv = *(const float4*)(base + 2 * DIM);
        *(float4*)&qs[sr][dq * 4] = qv;
        *(float4*)&ks[sr][dq * 4] = kv;
        *(float4*)&vs[sr][dq * 4] = vv;
    }
    __syncthreads();
    int s = tid >> 4, t = tid & 15;
    float sc = 0.f;
    #pragma unroll
    for (int d = 0; d < 64; ++d) sc += qs[s][d] * ks[t][d];
    sc *= 0.125f;
    float mx = sc;
    #pragma unroll
    for (int off = 1; off < 16; off <<= 1) mx = fmaxf(mx, __shfl_xor(mx, off, 16));
    float p = __expf(sc - mx);
    float sum = p;
    #pragma unroll
    for (int off = 1; off < 16; off <<= 1) sum += __shfl_xor(sum, off, 16);
    as_[s][t] = p / sum;
    __syncthreads();
    if (tid < 16) {
        float a = 0.f;
        #pragma unroll
        for (int ss = 0; ss < 16; ++ss) a += as_[ss][tid];
        amh[((size_t)(type * BB + b) * NN + g * GG + tid) * NH + hh] = a;
    }
    int s2 = tid >> 4, dg = (tid & 15) * 4;
    float o0 = 0, o1 = 0, o2 = 0, o3 = 0;
    #pragma unroll
    for (int t2 = 0; t2 < 16; ++t2) {
        float a2 = as_[s2][t2];
        o0 += a2 * vs[t2][dg];
        o1 += a2 * vs[t2][dg + 1];
        o2 += a2 * vs[t2][dg + 2];
        o3 += a2 * vs[t2][dg + 3];
    }
    int n2 = (type == 0) ? (s2 * GG + g) : (g * GG + s2);
    float* op = ((type == 0) ? orow : ocol) + (size_t)(b * NN + n2) * DIM + hh * 64 + dg;
    *(float4*)op = make_float4(o0, o1, o2, o3);
}

// one block per token row m: 8-layer divergence scalar + edge-token epilogue.
__global__ __launch_bounds__(256) void hfin_kernel(
    const float* __restrict__ h, const float* __restrict__ amh,
    const float* __restrict__ ew, const float* __restrict__ eb,
    unsigned short* __restrict__ hf)
{
    int m = blockIdx.x;                 // < 512
    int b = m >> 8, n = m & 255;
    int tid = threadIdx.x;
    __shared__ float divs;
    if (tid < 8) {
        const float* base = amh + (size_t)tid * 12288 + (size_t)b * 3072 + n * 12;
        float rs = 0.f, cs = 0.f;
        #pragma unroll
        for (int hh = 0; hh < NH; ++hh) {
            rs += base[hh];
            cs += base[6144 + hh];
        }
        float d = fabsf(rs - cs);
        d += __shfl_xor(d, 1);
        d += __shfl_xor(d, 2);
        d += __shfl_xor(d, 4);
        if (tid == 0) divs = d * (1.f / (NH * GG)) * (1.f / NL);
    }
    __syncthreads();
    float dv = divs;
    const float* hp = h + (size_t)m * DIM;
    unsigned short* yp = hf + (size_t)m * DIM;
    #pragma unroll
    for (int seg = 0; seg < 3; ++seg) {
        int d0 = tid + seg * 256;
        yp[d0] = bc(hp[d0] + dv * ew[d0] + eb[d0]);
    }
}

// S16[b][x][dy][oc][i] (bf16) = sum over dx,j of ax(x+dx-1,j)*P[b][dy*3+dx][oc][i*16+j]
__global__ __launch_bounds__(256) void s_kernel(const float* __restrict__ P,
                                               unsigned short* __restrict__ S16)
{
    int bdy = blockIdx.y;
    int b = bdy / 3, dy = bdy % 3;
    int ocg = blockIdx.x;
    __shared__ float Pl[3][4][16][17];
    int tid = threadIdx.x;
    #pragma unroll
    for (int l = 0; l < 12; ++l) {
        int e = l * 256 + tid;
        int dx = e >> 10, rem = e & 1023;
        int oc = rem >> 8, pix = rem & 255;
        int i = pix >> 4, j = pix & 15;
        Pl[dx][oc][j][i] =
            P[(((size_t)b * 9 + dy * 3 + dx) * 256 + ocg * 4 + oc) * 256 + pix];
    }
    __syncthreads();
    int xq = tid >> 6, oc = (tid >> 4) & 3, i = tid & 15;
    for (int xx = 0; xx < 64; ++xx) {
        int x = xq * 64 + xx;
        float acc = 0.f;
        #pragma unroll
        for (int dx = 0; dx < 3; ++dx) {
            int u = x + dx - 1;
            float p = (u + 0.5f) * 0.0625f - 0.5f;
            float fl = floorf(p);
            float f = p - fl;
            int j0 = (int)fl;
            int ja = j0 < 0 ? 0 : j0;
            int jb = (j0 + 1 > 15) ? 15 : (j0 + 1);
            bool valid = (u >= 0) && (u <= 255);
            float w0 = valid ? 1.f - f : 0.f;
            float w1 = valid ? f : 0.f;
            acc += w0 * Pl[dx][oc][ja][i] + w1 * Pl[dx][oc][jb][i];
        }
        S16[(((size_t)(b * 256 + x) * 3 + dy) * 256 + ocg * 4 + oc) * 16 + i] = bc(acc);
    }
}

// out[b][y][x]; S16 slab per (b,x): [dy][oc][i] = 12288 bf16, expanded to fp32 LDS
__global__ __launch_bounds__(256) void out_kernel(
    const unsigned short* __restrict__ S16, const float* __restrict__ b1,
    const float* __restrict__ w2, const float* __restrict__ b2p,
    float* __restrict__ out)
{
    int b = blockIdx.x >> 8, x = blockIdx.x & 255;
    __shared__ float Sl[12288];
    const unsigned short* Sp = S16 + (size_t)(b * 256 + x) * 12288;
    #pragma unroll
    for (int c = 0; c < 6; ++c) {
        int l8 = (c * 256 + threadIdx.x) * 8;
        u16x8 v = *(const u16x8*)(Sp + l8);
        #pragma unroll
        for (int j = 0; j < 8; ++j) Sl[l8 + j] = fbc(v[j]);
    }
    __syncthreads();
    int y = threadIdx.x;
    float wy[3][2];
    int iy[3][2];
    #pragma unroll
    for (int dy = 0; dy < 3; ++dy) {
        int v = y + dy - 1;
        if (v < 0 || v > 255) {
            wy[dy][0] = wy[dy][1] = 0.f;
            iy[dy][0] = iy[dy][1] = 0;
        } else {
            float pp = (v + 0.5f) * 0.0625f - 0.5f;
            float fl = floorf(pp);
            float f = pp - fl;
            int i0 = (int)fl;
            iy[dy][0] = i0 < 0 ? 0 : i0;
            iy[dy][1] = (i0 + 1 > 15) ? 15 : (i0 + 1);
            wy[dy][0] = 1.f - f;
            wy[dy][1] = f;
        }
    }
    float acc = 0.f;
    for (int oc = 0; oc < 256; ++oc) {
        float sv = 0.f;
        #pragma unroll
        for (int dy = 0; dy < 3; ++dy)
            sv += wy[dy][0] * Sl[dy * 4096 + oc * 16 + iy[dy][0]]
                + wy[dy][1] * Sl[dy * 4096 + oc * 16 + iy[dy][1]];
        sv += b1[oc];
        acc += fmaxf(sv, 0.f) * w2[oc];
    }
    out[(size_t)b * 65536 + y * 256 + x] = acc + b2p[0];
}

extern "C" void kernel_launch(void* const* d_in, const int* in_sizes, int n_in,
                              void* d_out, int out_size, void* d_ws, size_t ws_size,
                              hipStream_t stream)
{
    const float* x         = (const float*)d_in[0];
    const float* patch_w   = (const float*)d_in[1];
    const float* patch_b   = (const float*)d_in[2];
    const float* pos_embed = (const float*)d_in[3];
    const float* in_proj_w = (const float*)d_in[4];
    const float* in_proj_b = (const float*)d_in[5];
    const float* out_w     = (const float*)d_in[6];
    const float* out_b     = (const float*)d_in[7];
    const float* ln1_g     = (const float*)d_in[8];
    const float* ln1_b     = (const float*)d_in[9];
    const float* ln2_g     = (const float*)d_in[10];
    const float* ln2_b     = (const float*)d_in[11];
    const float* ffn_w1    = (const float*)d_in[12];
    const float* ffn_b1    = (const float*)d_in[13];
    const float* ffn_w2    = (const float*)d_in[14];
    const float* ffn_b2    = (const float*)d_in[15];
    const float* edge_w    = (const float*)d_in[16];
    const float* edge_b    = (const float*)d_in[17];
    const float* conv1_w   = (const float*)d_in[18];
    const float* conv1_b   = (const float*)d_in[19];
    const float* conv2_w   = (const float*)d_in[20];
    const float* conv2_b   = (const float*)d_in[21];
    float* out = (float*)d_out;
    float* ws = (float*)d_ws;

    float* h      = ws;                        // 393216
    float* qkv    = h + 393216;                // 1179648
    float* orow   = qkv + 1179648;             // 393216
    float* ocol   = orow + 393216;             // 393216
    float* Pb     = ocol + 393216;             // 1179648
    float* amh    = Pb + 1179648;              // 98304
    float2* pstat = (float2*)(amh + 98304);    // 512*48 float2 = 49152 floats
    unsigned short* Sb16   = (unsigned short*)(amh + 98304 + 49152);   // 6291456
    unsigned short* hid16  = Sb16 + 6291456;                           // 1048576
    unsigned short* hfin16 = hid16 + 1048576;                          // 393216
    unsigned short* Wct16  = hfin16 + 393216;                          // 1769472
    unsigned short* pw16   = Wct16 + 1769472;                          // 589824
    unsigned short* ipw16  = pw16 + 589824;                            // 8*IPW_N
    unsigned short* ow16   = ipw16 + 8 * IPW_N;                        // 8*OW_N
    unsigned short* f116   = ow16 + 8 * OW_N;                          // 8*F1_N
    unsigned short* f216   = f116 + 8 * F1_N;                          // 8*F2_N

    // streaming conversion: lane-contiguous 16B loads / 8B stores, no LDS
    cvtflat_kernel<<<dim3(3456, 5), 256, 0, stream>>>(
        in_proj_w, out_w, ffn_w1, ffn_w2, patch_w,
        ipw16, ow16, f116, f216, pw16);
    wct_kernel<<<dim3(256), 256, 0, stream>>>(conv1_w, Wct16);

    // patch embed: A = x via im2col (fp32), B = pw16; writes pstat partials
    gemm_bf16<MB | MPOS | MAIM2 | MSTATP, 32><<<dim3(24 * 16), 256, 0, stream>>>(
        x, nullptr, pw16, patch_b, pos_embed, nullptr, nullptr, nullptr, pstat,
        h, nullptr, 512, 768, 768, 1, 0, 0, 0, 0);

    for (int l = 0; l < NL; ++l) {
        gemm_bf16<MB | MLNA, 64><<<dim3(36 * 16), 256, 0, stream>>>(
            h, nullptr, ipw16 + (size_t)l * IPW_N, in_proj_b + (size_t)l * 2304, nullptr,
            pstat, ln1_g + l * DIM, ln1_b + l * DIM, nullptr, qkv, nullptr,
            512, 2304, 768, 1, 0, 0, 0, 0);
        attn_kernel<<<dim3(BB * GG, 2, NH), 256, 0, stream>>>(
            qkv, orow, ocol, amh + (size_t)l * 12288);
        gemm_bf16<MB2 | MRES | MAS2 | MSTATP, 32><<<dim3(24 * 16), 256, 0, stream>>>(
            orow, ocol, ow16 + (size_t)l * OW_N, out_b + (size_t)l * DIM, nullptr,
            nullptr, nullptr, nullptr, pstat, h, nullptr,
            512, 768, 768, 1, 0, 0, 0, 0);
        gemm_bf16<MB | MRELU | MOBF16 | MLNA, 64><<<dim3(32 * 16), 256, 0, stream>>>(
            h, nullptr, f116 + (size_t)l * F1_N, ffn_b1 + (size_t)l * FFD, nullptr,
            pstat, ln2_g + l * DIM, ln2_b + l * DIM, nullptr, nullptr, hid16,
            512, 2048, 768, 1, 0, 0, 0, 0);
        gemm_bf16<MB | MRES | MSTATP, 32><<<dim3(24 * 16), 256, 0, stream>>>(
            hid16, nullptr, f216 + (size_t)l * F2_N, ffn_b2 + (size_t)l * DIM, nullptr,
            nullptr, nullptr, nullptr, pstat, h, nullptr,
            512, 768, 2048, 1, 0, 0, 0, 0);
    }

    hfin_kernel<<<dim3(512), 256, 0, stream>>>(h, amh, edge_w, edge_b, hfin16);
    // P[b][dydx][oc][n]: z = dydx*2 + b, grid (8*8, 18) — both operands bf16
    gemm_bf16<0, 32><<<dim3(8 * 8, 18), 256, 0, stream>>>(
        Wct16, nullptr, hfin16, nullptr, nullptr, nullptr, nullptr, nullptr, nullptr,
        Pb, nullptr, 256, 256, 768,
        2, 196608LL, 196608LL, 65536LL, 589824LL);
    s_kernel<<<dim3(64, 6), 256, 0, stream>>>(Pb, Sb16);
    out_kernel<<<dim3(512), 256, 0, stream>>>(Sb16, conv1_b, conv2_w, conv2_b, out);
}

// Round 13
// 592.683 us; speedup vs baseline: 1.0205x; 1.0205x over previous
//
#include <hip/hip_runtime.h>
#include <hip/hip_bf16.h>
#include <math.h>

#define BB 2
#define CIN 3
#define IMGS 256
#define PS 16
#define GG 16
#define NN 256
#define DIM 768
#define NH 12
#define NL 8
#define FFD 2048
#define LNEPS 1e-5f

typedef __attribute__((ext_vector_type(8))) short bf16x8;
typedef __attribute__((ext_vector_type(8))) unsigned short u16x8;
typedef __attribute__((ext_vector_type(4))) float f32x4;

// ---- gemm mode flags ----
#define MB     1    // add bias[col]
#define MB2    2    // bias * 2 (implies bias)
#define MPOS   4    // add pos_embed[(row%256)*N + col]
#define MRELU  8
#define MRES   16   // C += result (residual, fp32)
#define MOBF16 32   // write bf16 to C16 instead of fp32 C
#define MAS2   64   // A = two fp32 arrays, summed + converted during staging
#define MBF32  128  // B = fp32 array, converted during reg-staging
#define MLNA   256  // A = fp32 h + layernorm; stats reduced from pstat partials
#define MAIM2  512  // A = raw image x, im2col during staging (fp32)
#define MSTATP 1024 // epilogue: write per-wave (sum,sumsq) row partials (BN=32,N=768)

__device__ inline unsigned short bc(float f) {
    return __builtin_bit_cast(unsigned short, __float2bfloat16(f));
}
__device__ inline float fbc(unsigned short u) {
    unsigned int x = ((unsigned int)u) << 16;
    return __builtin_bit_cast(float, x);
}

__device__ inline void gload16(const unsigned short* g, unsigned short* l) {
    __builtin_amdgcn_global_load_lds((const __attribute__((address_space(1))) void*)g,
                                     (__attribute__((address_space(3))) void*)l, 16, 0, 0);
}

// C[M,N] = A[M,K] * B[N,K]^T + epilogue. Tile BM=32 x BN (32 or 64), 4 waves
// (2x2; each wave 16 x 16*NI). B: bf16 via global_load_lds, or fp32 reg-staged
// with in-loop cvt (MBF32 — weights consumed once/pass, avoids the cvt
// round-trip). A: bf16 gload_lds unless reg-staged (MAS2/MLNA/MAIM2).
// 1-D grid, m204 chunked XCD swizzle, bx-major ids. LDS linear dest;
// XOR swizzle both sides (rule #21). MLNA: prologue reduces 48 pstat
// partials/row -> sstat. MSTATP: per-wave row partials (no atomics).
template<int MODE, int BN>
__global__ __launch_bounds__(256) void gemm_bf16(
    const void* __restrict__ Av, const void* __restrict__ A2v,
    const void* __restrict__ Bv,
    const float* __restrict__ bias, const float* __restrict__ pos,
    const float2* __restrict__ pstat,
    const float* __restrict__ lng, const float* __restrict__ lnb,
    float2* __restrict__ pstatOut,
    float* __restrict__ C, unsigned short* __restrict__ C16,
    int M, int N, int K, int zdiv,
    long long sAo, long long sBi, long long sCo, long long sCi)
{
    constexpr int NI = BN / 32;
    int z = blockIdx.y;
    int zo = z / zdiv, zi = z % zdiv;
    const unsigned short* A16 = (const unsigned short*)Av + (size_t)zo * sAo;
    const float* Af  = (const float*)Av  + (size_t)zo * sAo;
    const float* Af2 = (const float*)A2v + (size_t)zo * sAo;
    const unsigned short* B16 = (const unsigned short*)Bv + (size_t)zi * sBi;
    const float* Bf = (const float*)Bv + (size_t)zi * sBi;
    long long coff = (long long)zo * sCo + (long long)zi * sCi;

    int NBY = M >> 5;
    int nbysh = 31 - __builtin_clz(NBY);
    int id = blockIdx.x;
    int qch = gridDim.x >> 3;
    int wgid = (id & 7) * qch + (id >> 3);
    int bx = wgid >> nbysh, by = wgid & (NBY - 1);
    int bm = by * 32, bn = bx * BN;

    __shared__ __align__(16) unsigned short As[2][2048], Bs[2][BN * 64];
    __shared__ float2 sstat[32];
    int tid = threadIdx.x;
    int lane = tid & 63, wave = tid >> 6;
    int wr = wave >> 1, wc = wave & 1;
    int sA = tid;
    int srowA = sA >> 3, schkA = (sA & 7) ^ (srowA & 7);

    if constexpr (MODE & MLNA) {
        // reduce 48 partials per row (8 thr/row, 6 float2 each, coalesced)
        int row = tid >> 3, j = tid & 7;
        const float2* pr = pstat + (size_t)(bm + row) * 48 + j * 6;
        float s = 0.f, s2 = 0.f;
        #pragma unroll
        for (int k = 0; k < 6; ++k) { float2 v = pr[k]; s += v.x; s2 += v.y; }
        #pragma unroll
        for (int m2 = 1; m2 < 8; m2 <<= 1) {
            s  += __shfl_xor(s, m2);
            s2 += __shfl_xor(s2, m2);
        }
        if (j == 0) {
            float mean = s * (1.f / DIM);
            float var = s2 * (1.f / DIM) - mean * mean;
            sstat[row] = make_float2(mean, rsqrtf(var + LNEPS));
        }
        __syncthreads();
    }

    f32x4 acc[NI] = {};
    f32x4 rA0, rA1, rA20, rA21, rB[NI][2], gv0, gv1, bv0, bv1;
    float2 strow;

    auto gstageA = [&](int b, int kt) {
        gload16(A16 + (size_t)(bm + srowA) * K + kt * 64 + schkA * 8, &As[b][sA * 8]);
    };
    auto gstageB = [&](int b, int kt) {
        #pragma unroll
        for (int i = 0; i < NI; ++i) {
            int s = tid + i * 256;
            int row = s >> 3, chk = (s & 7) ^ (row & 7);
            gload16(B16 + (size_t)(bn + row) * K + kt * 64 + chk * 8, &Bs[b][s * 8]);
        }
    };
    auto ldA = [&](int kt) {
        int k0 = kt * 64 + schkA * 8;
        if constexpr (MODE & MAIM2) {
            int m = bm + srowA;
            int bq = m >> 8, n = m & 255, gy = n >> 4, gx = n & 15;
            int c = k0 >> 8, rem = k0 & 255, py = rem >> 4, px = rem & 15;
            const float* src = Af + (((size_t)(bq * CIN + c) * IMGS + gy * PS + py) << 8)
                             + gx * PS + px;
            rA0 = *(const f32x4*)(src);
            rA1 = *(const f32x4*)(src + 4);
        } else {
            size_t off = (size_t)(bm + srowA) * K + k0;
            rA0 = *(const f32x4*)(Af + off);
            rA1 = *(const f32x4*)(Af + off + 4);
            if constexpr (MODE & MAS2) {
                rA20 = *(const f32x4*)(Af2 + off);
                rA21 = *(const f32x4*)(Af2 + off + 4);
            }
            if constexpr (MODE & MLNA) {
                strow = sstat[srowA];
                gv0 = *(const f32x4*)(lng + k0); gv1 = *(const f32x4*)(lng + k0 + 4);
                bv0 = *(const f32x4*)(lnb + k0); bv1 = *(const f32x4*)(lnb + k0 + 4);
            }
        }
    };
    auto ldB = [&](int kt) {
        #pragma unroll
        for (int i = 0; i < NI; ++i) {
            int s = tid + i * 256;
            int row = s >> 3, chk = (s & 7) ^ (row & 7);
            size_t off = (size_t)(bn + row) * K + kt * 64 + chk * 8;
            rB[i][0] = *(const f32x4*)(Bf + off);
            rB[i][1] = *(const f32x4*)(Bf + off + 4);
        }
    };
    auto wrA = [&](int b) {
        bf16x8 v;
        #pragma unroll
        for (int j = 0; j < 4; ++j) {
            float x0 = rA0[j], x1 = rA1[j];
            if constexpr (MODE & MAS2) { x0 += rA20[j]; x1 += rA21[j]; }
            if constexpr (MODE & MLNA) {
                x0 = (x0 - strow.x) * strow.y * gv0[j] + bv0[j];
                x1 = (x1 - strow.x) * strow.y * gv1[j] + bv1[j];
            }
            v[j] = (short)bc(x0); v[4 + j] = (short)bc(x1);
        }
        *(bf16x8*)(&As[b][sA * 8]) = v;
    };
    auto wrB = [&](int b) {
        #pragma unroll
        for (int i = 0; i < NI; ++i) {
            int s = tid + i * 256;
            bf16x8 v;
            #pragma unroll
            for (int j = 0; j < 4; ++j) {
                v[j] = (short)bc(rB[i][0][j]); v[4 + j] = (short)bc(rB[i][1][j]);
            }
            *(bf16x8*)(&Bs[b][s * 8]) = v;
        }
    };
    constexpr bool regA = (MODE & (MAS2 | MLNA | MAIM2)) != 0;
    auto compute = [&](int b) {
        const unsigned short* Ab = As[b];
        const unsigned short* Bb = Bs[b];
        int rl = lane & 15, kh = lane >> 4;
        #pragma unroll
        for (int ks = 0; ks < 2; ++ks) {
            int kc = ks * 4 + kh;
            int ar = 16 * wr + rl;
            bf16x8 af = *(const bf16x8*)(Ab + ar * 64 + (kc ^ (ar & 7)) * 8);
            #pragma unroll
            for (int ni = 0; ni < NI; ++ni) {
                int br = 16 * NI * wc + 16 * ni + rl;
                bf16x8 bf = *(const bf16x8*)(Bb + br * 64 + (kc ^ (br & 7)) * 8);
                acc[ni] = __builtin_amdgcn_mfma_f32_16x16x32_bf16(af, bf, acc[ni], 0, 0, 0);
            }
        }
    };

    int nt = K >> 6;
    if constexpr (!regA) gstageA(0, 0); else { ldA(0); wrA(0); }
    if constexpr (!(MODE & MBF32)) gstageB(0, 0); else { ldB(0); wrB(0); }
    __syncthreads();
    int buf = 0;
    for (int t = 0; t < nt; ++t) {
        if (t + 1 < nt) {
            if constexpr (!regA) gstageA(buf ^ 1, t + 1); else ldA(t + 1);
            if constexpr (!(MODE & MBF32)) gstageB(buf ^ 1, t + 1); else ldB(t + 1);
        }
        compute(buf);
        if (t + 1 < nt) {
            if constexpr (regA) wrA(buf ^ 1);
            if constexpr (MODE & MBF32) wrB(buf ^ 1);
        }
        __syncthreads();
        buf ^= 1;
    }

    float vfin[4];
    #pragma unroll
    for (int ni = 0; ni < NI; ++ni) {
        #pragma unroll
        for (int r = 0; r < 4; ++r) {
            int row = bm + 16 * wr + (lane >> 4) * 4 + r;
            int col = bn + 16 * NI * wc + 16 * ni + (lane & 15);
            float v = acc[ni][r];
            if (MODE & (MB | MB2)) v += bias[col] * ((MODE & MB2) ? 2.f : 1.f);
            if (MODE & MPOS) v += pos[(size_t)(row & (NN - 1)) * N + col];
            if (MODE & MRELU) v = fmaxf(v, 0.f);
            long long ci = coff + (long long)row * N + col;
            if (MODE & MOBF16) { C16[ci] = bc(v); }
            else if (MODE & MRES) { v += C[ci]; C[ci] = v; }
            else { C[ci] = v; }
            if (ni == 0) vfin[r] = v;
        }
    }
    if constexpr (MODE & MSTATP) {
        // per-wave 16-col partials; lane&15==0 writes 4 rows (8B each, no atomics)
        #pragma unroll
        for (int r = 0; r < 4; ++r) {
            float s = vfin[r], s2 = vfin[r] * vfin[r];
            #pragma unroll
            for (int m2 = 1; m2 < 16; m2 <<= 1) {
                s  += __shfl_xor(s, m2);
                s2 += __shfl_xor(s2, m2);
            }
            if ((lane & 15) == 0) {
                int row = bm + 16 * wr + (lane >> 4) * 4 + r;
                pstatOut[(size_t)row * 48 + bx * 2 + wc] = make_float2(s, s2);
            }
        }
    }
}

// Wct16[dydx][oc][c] = bf16(conv1_w[oc][c][dy][dx]); one block per oc,
// coalesced 27KB read into LDS, coalesced bf16 writes. Needed because Wct
// is the P-GEMM's A operand, read 8x via gload_lds.
__global__ __launch_bounds__(256) void wct_kernel(const float* __restrict__ conv1_w,
                                                  unsigned short* __restrict__ Wct16)
{
    int oc = blockIdx.x;
    int tid = threadIdx.x;
    __shared__ float w[6912];
    const float* src = conv1_w + (size_t)oc * 6912;
    #pragma unroll
    for (int k = 0; k < 27; ++k) w[tid + k * 256] = src[tid + k * 256];
    __syncthreads();
    #pragma unroll
    for (int dydx = 0; dydx < 9; ++dydx) {
        #pragma unroll
        for (int k = 0; k < 3; ++k) {
            int c = tid + k * 256;
            Wct16[(size_t)dydx * 196608 + oc * 768 + c] = bc(w[c * 9 + dydx]);
        }
    }
}

// grid (B*G, 2 types, 12 heads). amh slice: [type][b][n][h] (per layer)
__global__ __launch_bounds__(256) void attn_kernel(
    const float* __restrict__ qkv, float* __restrict__ orow,
    float* __restrict__ ocol, float* __restrict__ amh)
{
    int b = blockIdx.x >> 4, g = blockIdx.x & 15;
    int type = blockIdx.y;
    int hh = blockIdx.z;
    int tid = threadIdx.x;
    __shared__ float qs[16][68], ks[16][68], vs[16][68], as_[16][17];
    {
        int sr = tid >> 4, dq = tid & 15;
        int n = (type == 0) ? (sr * GG + g) : (g * GG + sr);
        const float* base = qkv + (size_t)(b * NN + n) * (3 * DIM) + hh * 64 + dq * 4;
        float4 qv = *(const float4*)(base);
        float4 kv = *(const float4*)(base + DIM);
        float4 vv = *(const float4*)(base + 2 * DIM);
        *(float4*)&qs[sr][dq * 4] = qv;
        *(float4*)&ks[sr][dq * 4] = kv;
        *(float4*)&vs[sr][dq * 4] = vv;
    }
    __syncthreads();
    int s = tid >> 4, t = tid & 15;
    float sc = 0.f;
    #pragma unroll
    for (int d = 0; d < 64; ++d) sc += qs[s][d] * ks[t][d];
    sc *= 0.125f;
    float mx = sc;
    #pragma unroll
    for (int off = 1; off < 16; off <<= 1) mx = fmaxf(mx, __shfl_xor(mx, off, 16));
    float p = __expf(sc - mx);
    float sum = p;
    #pragma unroll
    for (int off = 1; off < 16; off <<= 1) sum += __shfl_xor(sum, off, 16);
    as_[s][t] = p / sum;
    __syncthreads();
    if (tid < 16) {
        float a = 0.f;
        #pragma unroll
        for (int ss = 0; ss < 16; ++ss) a += as_[ss][tid];
        amh[((size_t)(type * BB + b) * NN + g * GG + tid) * NH + hh] = a;
    }
    int s2 = tid >> 4, dg = (tid & 15) * 4;
    float o0 = 0, o1 = 0, o2 = 0, o3 = 0;
    #pragma unroll
    for (int t2 = 0; t2 < 16; ++t2) {
        float a2 = as_[s2][t2];
        o0 += a2 * vs[t2][dg];
        o1 += a2 * vs[t2][dg + 1];
        o2 += a2 * vs[t2][dg + 2];
        o3 += a2 * vs[t2][dg + 3];
    }
    int n2 = (type == 0) ? (s2 * GG + g) : (g * GG + s2);
    float* op = ((type == 0) ? orow : ocol) + (size_t)(b * NN + n2) * DIM + hh * 64 + dg;
    *(float4*)op = make_float4(o0, o1, o2, o3);
}

// one block per token row m: 8-layer divergence scalar + edge-token epilogue.
__global__ __launch_bounds__(256) void hfin_kernel(
    const float* __restrict__ h, const float* __restrict__ amh,
    const float* __restrict__ ew, const float* __restrict__ eb,
    unsigned short* __restrict__ hf)
{
    int m = blockIdx.x;                 // < 512
    int b = m >> 8, n = m & 255;
    int tid = threadIdx.x;
    __shared__ float divs;
    if (tid < 8) {
        const float* base = amh + (size_t)tid * 12288 + (size_t)b * 3072 + n * 12;
        float rs = 0.f, cs = 0.f;
        #pragma unroll
        for (int hh = 0; hh < NH; ++hh) {
            rs += base[hh];
            cs += base[6144 + hh];
        }
        float d = fabsf(rs - cs);
        d += __shfl_xor(d, 1);
        d += __shfl_xor(d, 2);
        d += __shfl_xor(d, 4);
        if (tid == 0) divs = d * (1.f / (NH * GG)) * (1.f / NL);
    }
    __syncthreads();
    float dv = divs;
    const float* hp = h + (size_t)m * DIM;
    unsigned short* yp = hf + (size_t)m * DIM;
    #pragma unroll
    for (int seg = 0; seg < 3; ++seg) {
        int d0 = tid + seg * 256;
        yp[d0] = bc(hp[d0] + dv * ew[d0] + eb[d0]);
    }
}

// S16[b][x][dy][oc][i] (bf16) = sum over dx,j of ax(x+dx-1,j)*P[b][dy*3+dx][oc][i*16+j]
__global__ __launch_bounds__(256) void s_kernel(const float* __restrict__ P,
                                               unsigned short* __restrict__ S16)
{
    int bdy = blockIdx.y;
    int b = bdy / 3, dy = bdy % 3;
    int ocg = blockIdx.x;
    __shared__ float Pl[3][4][16][17];
    int tid = threadIdx.x;
    #pragma unroll
    for (int l = 0; l < 12; ++l) {
        int e = l * 256 + tid;
        int dx = e >> 10, rem = e & 1023;
        int oc = rem >> 8, pix = rem & 255;
        int i = pix >> 4, j = pix & 15;
        Pl[dx][oc][j][i] =
            P[(((size_t)b * 9 + dy * 3 + dx) * 256 + ocg * 4 + oc) * 256 + pix];
    }
    __syncthreads();
    int xq = tid >> 6, oc = (tid >> 4) & 3, i = tid & 15;
    for (int xx = 0; xx < 64; ++xx) {
        int x = xq * 64 + xx;
        float acc = 0.f;
        #pragma unroll
        for (int dx = 0; dx < 3; ++dx) {
            int u = x + dx - 1;
            float p = (u + 0.5f) * 0.0625f - 0.5f;
            float fl = floorf(p);
            float f = p - fl;
            int j0 = (int)fl;
            int ja = j0 < 0 ? 0 : j0;
            int jb = (j0 + 1 > 15) ? 15 : (j0 + 1);
            bool valid = (u >= 0) && (u <= 255);
            float w0 = valid ? 1.f - f : 0.f;
            float w1 = valid ? f : 0.f;
            acc += w0 * Pl[dx][oc][ja][i] + w1 * Pl[dx][oc][jb][i];
        }
        S16[(((size_t)(b * 256 + x) * 3 + dy) * 256 + ocg * 4 + oc) * 16 + i] = bc(acc);
    }
}

// out[b][y][x]; S16 slab per (b,x): [dy][oc][i] = 12288 bf16, expanded to fp32 LDS
__global__ __launch_bounds__(256) void out_kernel(
    const unsigned short* __restrict__ S16, const float* __restrict__ b1,
    const float* __restrict__ w2, const float* __restrict__ b2p,
    float* __restrict__ out)
{
    int b = blockIdx.x >> 8, x = blockIdx.x & 255;
    __shared__ float Sl[12288];
    const unsigned short* Sp = S16 + (size_t)(b * 256 + x) * 12288;
    #pragma unroll
    for (int c = 0; c < 6; ++c) {
        int l8 = (c * 256 + threadIdx.x) * 8;
        u16x8 v = *(const u16x8*)(Sp + l8);
        #pragma unroll
        for (int j = 0; j < 8; ++j) Sl[l8 + j] = fbc(v[j]);
    }
    __syncthreads();
    int y = threadIdx.x;
    float wy[3][2];
    int iy[3][2];
    #pragma unroll
    for (int dy = 0; dy < 3; ++dy) {
        int v = y + dy - 1;
        if (v < 0 || v > 255) {
            wy[dy][0] = wy[dy][1] = 0.f;
            iy[dy][0] = iy[dy][1] = 0;
        } else {
            float pp = (v + 0.5f) * 0.0625f - 0.5f;
            float fl = floorf(pp);
            float f = pp - fl;
            int i0 = (int)fl;
            iy[dy][0] = i0 < 0 ? 0 : i0;
            iy[dy][1] = (i0 + 1 > 15) ? 15 : (i0 + 1);
            wy[dy][0] = 1.f - f;
            wy[dy][1] = f;
        }
    }
    float acc = 0.f;
    for (int oc = 0; oc < 256; ++oc) {
        float sv = 0.f;
        #pragma unroll
        for (int dy = 0; dy < 3; ++dy)
            sv += wy[dy][0] * Sl[dy * 4096 + oc * 16 + iy[dy][0]]
                + wy[dy][1] * Sl[dy * 4096 + oc * 16 + iy[dy][1]];
        sv += b1[oc];
        acc += fmaxf(sv, 0.f) * w2[oc];
    }
    out[(size_t)b * 65536 + y * 256 + x] = acc + b2p[0];
}

extern "C" void kernel_launch(void* const* d_in, const int* in_sizes, int n_in,
                              void* d_out, int out_size, void* d_ws, size_t ws_size,
                              hipStream_t stream)
{
    const float* x         = (const float*)d_in[0];
    const float* patch_w   = (const float*)d_in[1];
    const float* patch_b   = (const float*)d_in[2];
    const float* pos_embed = (const float*)d_in[3];
    const float* in_proj_w = (const float*)d_in[4];
    const float* in_proj_b = (const float*)d_in[5];
    const float* out_w     = (const float*)d_in[6];
    const float* out_b     = (const float*)d_in[7];
    const float* ln1_g     = (const float*)d_in[8];
    const float* ln1_b     = (const float*)d_in[9];
    const float* ln2_g     = (const float*)d_in[10];
    const float* ln2_b     = (const float*)d_in[11];
    const float* ffn_w1    = (const float*)d_in[12];
    const float* ffn_b1    = (const float*)d_in[13];
    const float* ffn_w2    = (const float*)d_in[14];
    const float* ffn_b2    = (const float*)d_in[15];
    const float* edge_w    = (const float*)d_in[16];
    const float* edge_b    = (const float*)d_in[17];
    const float* conv1_w   = (const float*)d_in[18];
    const float* conv1_b   = (const float*)d_in[19];
    const float* conv2_w   = (const float*)d_in[20];
    const float* conv2_b   = (const float*)d_in[21];
    float* out = (float*)d_out;
    float* ws = (float*)d_ws;

    float* h      = ws;                        // 393216
    float* qkv    = h + 393216;                // 1179648
    float* orow   = qkv + 1179648;             // 393216
    float* ocol   = orow + 393216;             // 393216
    float* Pb     = ocol + 393216;             // 1179648
    float* amh    = Pb + 1179648;              // 98304
    float2* pstat = (float2*)(amh + 98304);    // 512*48 float2 = 49152 floats
    unsigned short* Sb16   = (unsigned short*)(amh + 98304 + 49152);   // 6291456
    unsigned short* hid16  = Sb16 + 6291456;                           // 1048576
    unsigned short* hfin16 = hid16 + 1048576;                          // 393216
    unsigned short* Wct16  = hfin16 + 393216;                          // 1769472

    wct_kernel<<<dim3(256), 256, 0, stream>>>(conv1_w, Wct16);

    // patch embed: A = x via im2col (fp32), B = patch_w (fp32, reg-staged);
    // writes pstat partials for LN1 of layer 0
    gemm_bf16<MB | MPOS | MAIM2 | MBF32 | MSTATP, 32><<<dim3(24 * 16), 256, 0, stream>>>(
        x, nullptr, patch_w, patch_b, pos_embed, nullptr, nullptr, nullptr, pstat,
        h, nullptr, 512, 768, 768, 1, 0, 0, 0, 0);

    for (int l = 0; l < NL; ++l) {
        gemm_bf16<MB | MLNA | MBF32, 64><<<dim3(36 * 16), 256, 0, stream>>>(
            h, nullptr, in_proj_w + (size_t)l * 1769472,
            in_proj_b + (size_t)l * 2304, nullptr,
            pstat, ln1_g + l * DIM, ln1_b + l * DIM, nullptr, qkv, nullptr,
            512, 2304, 768, 1, 0, 0, 0, 0);
        attn_kernel<<<dim3(BB * GG, 2, NH), 256, 0, stream>>>(
            qkv, orow, ocol, amh + (size_t)l * 12288);
        gemm_bf16<MB2 | MRES | MAS2 | MBF32 | MSTATP, 32><<<dim3(24 * 16), 256, 0, stream>>>(
            orow, ocol, out_w + (size_t)l * 589824,
            out_b + (size_t)l * DIM, nullptr,
            nullptr, nullptr, nullptr, pstat, h, nullptr,
            512, 768, 768, 1, 0, 0, 0, 0);
        gemm_bf16<MB | MRELU | MOBF16 | MLNA | MBF32, 64><<<dim3(32 * 16), 256, 0, stream>>>(
            h, nullptr, ffn_w1 + (size_t)l * 1572864,
            ffn_b1 + (size_t)l * FFD, nullptr,
            pstat, ln2_g + l * DIM, ln2_b + l * DIM, nullptr, nullptr, hid16,
            512, 2048, 768, 1, 0, 0, 0, 0);
        gemm_bf16<MB | MRES | MBF32 | MSTATP, 32><<<dim3(24 * 16), 256, 0, stream>>>(
            hid16, nullptr, ffn_w2 + (size_t)l * 1572864,
            ffn_b2 + (size_t)l * DIM, nullptr,
            nullptr, nullptr, nullptr, pstat, h, nullptr,
            512, 768, 2048, 1, 0, 0, 0, 0);
    }

    hfin_kernel<<<dim3(512), 256, 0, stream>>>(h, amh, edge_w, edge_b, hfin16);
    // P[b][dydx][oc][n]: z = dydx*2 + b, grid (8*8, 18) — both operands bf16
    gemm_bf16<0, 32><<<dim3(8 * 8, 18), 256, 0, stream>>>(
        Wct16, nullptr, hfin16, nullptr, nullptr, nullptr, nullptr, nullptr, nullptr,
        Pb, nullptr, 256, 256, 768,
        2, 196608LL, 196608LL, 65536LL, 589824LL);
    s_kernel<<<dim3(64, 6), 256, 0, stream>>>(Pb, Sb16);
    out_kernel<<<dim3(512), 256, 0, stream>>>(Sb16, conv1_b, conv2_w, conv2_b, out);
}

// Round 14
// 559.235 us; speedup vs baseline: 1.0815x; 1.0598x over previous
//
#include <hip/hip_runtime.h>
#include <hip/hip_bf16.h>
#include <math.h>

#define BB 2
#define CIN 3
#define IMGS 256
#define PS 16
#define GG 16
#define NN 256
#define DIM 768
#define NH 12
#define NL 8
#define FFD 2048
#define LNEPS 1e-5f

typedef __attribute__((ext_vector_type(8))) short bf16x8;
typedef __attribute__((ext_vector_type(8))) unsigned short u16x8;
typedef __attribute__((ext_vector_type(4))) float f32x4;

// ---- gemm mode flags ----
#define MB     1    // add bias[col]
#define MB2    2    // bias * 2 (implies bias)
#define MPOS   4    // add pos_embed[(row%256)*N + col]
#define MRELU  8
#define MRES   16   // C += result (residual, fp32)
#define MOBF16 32   // write bf16 to C16 instead of fp32 C
#define MAS2   64   // A = two fp32 arrays, summed + converted during staging
#define MBF32  128  // B = fp32 array, converted during reg-staging
#define MLNA   256  // A = fp32 h + layernorm; stats reduced from pstat partials
#define MAIM2  512  // A = raw image x, im2col during staging (fp32)
#define MSTATP 1024 // epilogue: write per-wave (sum,sumsq) row partials (BN=32,N=768)

__device__ inline unsigned short bc(float f) {
    return __builtin_bit_cast(unsigned short, __float2bfloat16(f));
}
__device__ inline float fbc(unsigned short u) {
    unsigned int x = ((unsigned int)u) << 16;
    return __builtin_bit_cast(float, x);
}

__device__ inline void gload16(const unsigned short* g, unsigned short* l) {
    __builtin_amdgcn_global_load_lds((const __attribute__((address_space(1))) void*)g,
                                     (__attribute__((address_space(3))) void*)l, 16, 0, 0);
}

// C[M,N] = A[M,K] * B[N,K]^T + epilogue. Tile BM=32 x BN (32 or 64), 4 waves
// (2x2; each wave 16 x 16*NI). K_STEP=128: halves barrier count vs 64 (these
// GEMMs are latency/barrier-bound at 1.5-2.25 blocks/CU; m233). K % 128 == 0.
// B: bf16 via global_load_lds, or fp32 reg-staged with in-loop cvt (MBF32).
// A: bf16 gload_lds unless reg-staged (MAS2/MLNA/MAIM2). 1-D grid, m204
// chunked XCD swizzle, bx-major ids. LDS linear dest; XOR swizzle both sides.
template<int MODE, int BN>
__global__ __launch_bounds__(256) void gemm_bf16(
    const void* __restrict__ Av, const void* __restrict__ A2v,
    const void* __restrict__ Bv,
    const float* __restrict__ bias, const float* __restrict__ pos,
    const float2* __restrict__ pstat,
    const float* __restrict__ lng, const float* __restrict__ lnb,
    float2* __restrict__ pstatOut,
    float* __restrict__ C, unsigned short* __restrict__ C16,
    int M, int N, int K, int zdiv,
    long long sAo, long long sBi, long long sCo, long long sCi)
{
    constexpr int NI = BN / 32;
    constexpr int BS = BN / 16;     // B slots per thread (2 or 4)
    int z = blockIdx.y;
    int zo = z / zdiv, zi = z % zdiv;
    const unsigned short* A16 = (const unsigned short*)Av + (size_t)zo * sAo;
    const float* Af  = (const float*)Av  + (size_t)zo * sAo;
    const float* Af2 = (const float*)A2v + (size_t)zo * sAo;
    const unsigned short* B16 = (const unsigned short*)Bv + (size_t)zi * sBi;
    const float* Bf = (const float*)Bv + (size_t)zi * sBi;
    long long coff = (long long)zo * sCo + (long long)zi * sCi;

    int NBY = M >> 5;
    int nbysh = 31 - __builtin_clz(NBY);
    int id = blockIdx.x;
    int qch = gridDim.x >> 3;
    int wgid = (id & 7) * qch + (id >> 3);
    int bx = wgid >> nbysh, by = wgid & (NBY - 1);
    int bm = by * 32, bn = bx * BN;

    __shared__ __align__(16) unsigned short As[2][4096], Bs[2][BN * 128];
    __shared__ float2 sstat[32];
    int tid = threadIdx.x;
    int lane = tid & 63, wave = tid >> 6;
    int wr = wave >> 1, wc = wave & 1;

    if constexpr (MODE & MLNA) {
        int row = tid >> 3, j = tid & 7;
        const float2* pr = pstat + (size_t)(bm + row) * 48 + j * 6;
        float s = 0.f, s2 = 0.f;
        #pragma unroll
        for (int k = 0; k < 6; ++k) { float2 v = pr[k]; s += v.x; s2 += v.y; }
        #pragma unroll
        for (int m2 = 1; m2 < 8; m2 <<= 1) {
            s  += __shfl_xor(s, m2);
            s2 += __shfl_xor(s2, m2);
        }
        if (j == 0) {
            float mean = s * (1.f / DIM);
            float var = s2 * (1.f / DIM) - mean * mean;
            sstat[row] = make_float2(mean, rsqrtf(var + LNEPS));
        }
        __syncthreads();
    }

    f32x4 acc[NI] = {};
    f32x4 rA[2][2], rA2[2][2], rB[BS][2], gv[2][2], bv[2][2];
    float2 strowv[2];

    auto gstageA = [&](int b, int kt) {
        #pragma unroll
        for (int i = 0; i < 2; ++i) {
            int s = tid + i * 256;
            int row = s >> 4, chk = (s & 15) ^ (row & 7);
            gload16(A16 + (size_t)(bm + row) * K + kt * 128 + chk * 8, &As[b][s * 8]);
        }
    };
    auto gstageB = [&](int b, int kt) {
        #pragma unroll
        for (int i = 0; i < BS; ++i) {
            int s = tid + i * 256;
            int row = s >> 4, chk = (s & 15) ^ (row & 7);
            gload16(B16 + (size_t)(bn + row) * K + kt * 128 + chk * 8, &Bs[b][s * 8]);
        }
    };
    auto ldA = [&](int kt) {
        #pragma unroll
        for (int i = 0; i < 2; ++i) {
            int s = tid + i * 256;
            int row = s >> 4;
            int k0 = kt * 128 + (((s & 15) ^ (row & 7)) * 8);
            if constexpr (MODE & MAIM2) {
                int m = bm + row;
                int bq = m >> 8, n = m & 255, gy = n >> 4, gx = n & 15;
                int c = k0 >> 8, rem = k0 & 255, py = rem >> 4, px = rem & 15;
                const float* src = Af + (((size_t)(bq * CIN + c) * IMGS + gy * PS + py) << 8)
                                 + gx * PS + px;
                rA[i][0] = *(const f32x4*)(src);
                rA[i][1] = *(const f32x4*)(src + 4);
            } else {
                size_t off = (size_t)(bm + row) * K + k0;
                rA[i][0] = *(const f32x4*)(Af + off);
                rA[i][1] = *(const f32x4*)(Af + off + 4);
                if constexpr (MODE & MAS2) {
                    rA2[i][0] = *(const f32x4*)(Af2 + off);
                    rA2[i][1] = *(const f32x4*)(Af2 + off + 4);
                }
                if constexpr (MODE & MLNA) {
                    strowv[i] = sstat[row];
                    gv[i][0] = *(const f32x4*)(lng + k0); gv[i][1] = *(const f32x4*)(lng + k0 + 4);
                    bv[i][0] = *(const f32x4*)(lnb + k0); bv[i][1] = *(const f32x4*)(lnb + k0 + 4);
                }
            }
        }
    };
    auto ldB = [&](int kt) {
        #pragma unroll
        for (int i = 0; i < BS; ++i) {
            int s = tid + i * 256;
            int row = s >> 4, chk = (s & 15) ^ (row & 7);
            size_t off = (size_t)(bn + row) * K + kt * 128 + chk * 8;
            rB[i][0] = *(const f32x4*)(Bf + off);
            rB[i][1] = *(const f32x4*)(Bf + off + 4);
        }
    };
    auto wrA = [&](int b) {
        #pragma unroll
        for (int i = 0; i < 2; ++i) {
            int s = tid + i * 256;
            bf16x8 v;
            #pragma unroll
            for (int j = 0; j < 4; ++j) {
                float x0 = rA[i][0][j], x1 = rA[i][1][j];
                if constexpr (MODE & MAS2) { x0 += rA2[i][0][j]; x1 += rA2[i][1][j]; }
                if constexpr (MODE & MLNA) {
                    x0 = (x0 - strowv[i].x) * strowv[i].y * gv[i][0][j] + bv[i][0][j];
                    x1 = (x1 - strowv[i].x) * strowv[i].y * gv[i][1][j] + bv[i][1][j];
                }
                v[j] = (short)bc(x0); v[4 + j] = (short)bc(x1);
            }
            *(bf16x8*)(&As[b][s * 8]) = v;
        }
    };
    auto wrB = [&](int b) {
        #pragma unroll
        for (int i = 0; i < BS; ++i) {
            int s = tid + i * 256;
            bf16x8 v;
            #pragma unroll
            for (int j = 0; j < 4; ++j) {
                v[j] = (short)bc(rB[i][0][j]); v[4 + j] = (short)bc(rB[i][1][j]);
            }
            *(bf16x8*)(&Bs[b][s * 8]) = v;
        }
    };
    constexpr bool regA = (MODE & (MAS2 | MLNA | MAIM2)) != 0;
    auto compute = [&](int b) {
        const unsigned short* Ab = As[b];
        const unsigned short* Bb = Bs[b];
        int rl = lane & 15, kh = lane >> 4;
        #pragma unroll
        for (int ks = 0; ks < 4; ++ks) {
            int kc = ks * 4 + kh;               // 0..15
            int ar = 16 * wr + rl;
            bf16x8 af = *(const bf16x8*)(Ab + ar * 128 + (kc ^ (ar & 7)) * 8);
            #pragma unroll
            for (int ni = 0; ni < NI; ++ni) {
                int br = 16 * NI * wc + 16 * ni + rl;
                bf16x8 bf = *(const bf16x8*)(Bb + br * 128 + (kc ^ (br & 7)) * 8);
                acc[ni] = __builtin_amdgcn_mfma_f32_16x16x32_bf16(af, bf, acc[ni], 0, 0, 0);
            }
        }
    };

    int nt = K >> 7;
    if constexpr (!regA) gstageA(0, 0); else { ldA(0); wrA(0); }
    if constexpr (!(MODE & MBF32)) gstageB(0, 0); else { ldB(0); wrB(0); }
    __syncthreads();
    int buf = 0;
    for (int t = 0; t < nt; ++t) {
        if (t + 1 < nt) {
            if constexpr (!regA) gstageA(buf ^ 1, t + 1); else ldA(t + 1);
            if constexpr (!(MODE & MBF32)) gstageB(buf ^ 1, t + 1); else ldB(t + 1);
        }
        compute(buf);
        if (t + 1 < nt) {
            if constexpr (regA) wrA(buf ^ 1);
            if constexpr (MODE & MBF32) wrB(buf ^ 1);
        }
        __syncthreads();
        buf ^= 1;
    }

    float vfin[4];
    #pragma unroll
    for (int ni = 0; ni < NI; ++ni) {
        #pragma unroll
        for (int r = 0; r < 4; ++r) {
            int row = bm + 16 * wr + (lane >> 4) * 4 + r;
            int col = bn + 16 * NI * wc + 16 * ni + (lane & 15);
            float v = acc[ni][r];
            if (MODE & (MB | MB2)) v += bias[col] * ((MODE & MB2) ? 2.f : 1.f);
            if (MODE & MPOS) v += pos[(size_t)(row & (NN - 1)) * N + col];
            if (MODE & MRELU) v = fmaxf(v, 0.f);
            long long ci = coff + (long long)row * N + col;
            if (MODE & MOBF16) { C16[ci] = bc(v); }
            else if (MODE & MRES) { v += C[ci]; C[ci] = v; }
            else { C[ci] = v; }
            if (ni == 0) vfin[r] = v;
        }
    }
    if constexpr (MODE & MSTATP) {
        #pragma unroll
        for (int r = 0; r < 4; ++r) {
            float s = vfin[r], s2 = vfin[r] * vfin[r];
            #pragma unroll
            for (int m2 = 1; m2 < 16; m2 <<= 1) {
                s  += __shfl_xor(s, m2);
                s2 += __shfl_xor(s2, m2);
            }
            if ((lane & 15) == 0) {
                int row = bm + 16 * wr + (lane >> 4) * 4 + r;
                pstatOut[(size_t)row * 48 + bx * 2 + wc] = make_float2(s, s2);
            }
        }
    }
}

// Wct16[dydx][oc][c] = bf16(conv1_w[oc][c][dy][dx]); one block per oc.
__global__ __launch_bounds__(256) void wct_kernel(const float* __restrict__ conv1_w,
                                                  unsigned short* __restrict__ Wct16)
{
    int oc = blockIdx.x;
    int tid = threadIdx.x;
    __shared__ float w[6912];
    const float* src = conv1_w + (size_t)oc * 6912;
    #pragma unroll
    for (int k = 0; k < 27; ++k) w[tid + k * 256] = src[tid + k * 256];
    __syncthreads();
    #pragma unroll
    for (int dydx = 0; dydx < 9; ++dydx) {
        #pragma unroll
        for (int k = 0; k < 3; ++k) {
            int c = tid + k * 256;
            Wct16[(size_t)dydx * 196608 + oc * 768 + c] = bc(w[c * 9 + dydx]);
        }
    }
}

// grid (B*G, 2 types, 12 heads). amh slice: [type][b][n][h] (per layer)
__global__ __launch_bounds__(256) void attn_kernel(
    const float* __restrict__ qkv, float* __restrict__ orow,
    float* __restrict__ ocol, float* __restrict__ amh)
{
    int b = blockIdx.x >> 4, g = blockIdx.x & 15;
    int type = blockIdx.y;
    int hh = blockIdx.z;
    int tid = threadIdx.x;
    __shared__ float qs[16][68], ks[16][68], vs[16][68], as_[16][17];
    {
        int sr = tid >> 4, dq = tid & 15;
        int n = (type == 0) ? (sr * GG + g) : (g * GG + sr);
        const float* base = qkv + (size_t)(b * NN + n) * (3 * DIM) + hh * 64 + dq * 4;
        float4 qv = *(const float4*)(base);
        float4 kv = *(const float4*)(base + DIM);
        float4 vv = *(const float4*)(base + 2 * DIM);
        *(float4*)&qs[sr][dq * 4] = qv;
        *(float4*)&ks[sr][dq * 4] = kv;
        *(float4*)&vs[sr][dq * 4] = vv;
    }
    __syncthreads();
    int s = tid >> 4, t = tid & 15;
    float sc = 0.f;
    #pragma unroll
    for (int d = 0; d < 64; ++d) sc += qs[s][d] * ks[t][d];
    sc *= 0.125f;
    float mx = sc;
    #pragma unroll
    for (int off = 1; off < 16; off <<= 1) mx = fmaxf(mx, __shfl_xor(mx, off, 16));
    float p = __expf(sc - mx);
    float sum = p;
    #pragma unroll
    for (int off = 1; off < 16; off <<= 1) sum += __shfl_xor(sum, off, 16);
    as_[s][t] = p / sum;
    __syncthreads();
    if (tid < 16) {
        float a = 0.f;
        #pragma unroll
        for (int ss = 0; ss < 16; ++ss) a += as_[ss][tid];
        amh[((size_t)(type * BB + b) * NN + g * GG + tid) * NH + hh] = a;
    }
    int s2 = tid >> 4, dg = (tid & 15) * 4;
    float o0 = 0, o1 = 0, o2 = 0, o3 = 0;
    #pragma unroll
    for (int t2 = 0; t2 < 16; ++t2) {
        float a2 = as_[s2][t2];
        o0 += a2 * vs[t2][dg];
        o1 += a2 * vs[t2][dg + 1];
        o2 += a2 * vs[t2][dg + 2];
        o3 += a2 * vs[t2][dg + 3];
    }
    int n2 = (type == 0) ? (s2 * GG + g) : (g * GG + s2);
    float* op = ((type == 0) ? orow : ocol) + (size_t)(b * NN + n2) * DIM + hh * 64 + dg;
    *(float4*)op = make_float4(o0, o1, o2, o3);
}

// one block per token row m: 8-layer divergence scalar + edge-token epilogue.
__global__ __launch_bounds__(256) void hfin_kernel(
    const float* __restrict__ h, const float* __restrict__ amh,
    const float* __restrict__ ew, const float* __restrict__ eb,
    unsigned short* __restrict__ hf)
{
    int m = blockIdx.x;                 // < 512
    int b = m >> 8, n = m & 255;
    int tid = threadIdx.x;
    __shared__ float divs;
    if (tid < 8) {
        const float* base = amh + (size_t)tid * 12288 + (size_t)b * 3072 + n * 12;
        float rs = 0.f, cs = 0.f;
        #pragma unroll
        for (int hh = 0; hh < NH; ++hh) {
            rs += base[hh];
            cs += base[6144 + hh];
        }
        float d = fabsf(rs - cs);
        d += __shfl_xor(d, 1);
        d += __shfl_xor(d, 2);
        d += __shfl_xor(d, 4);
        if (tid == 0) divs = d * (1.f / (NH * GG)) * (1.f / NL);
    }
    __syncthreads();
    float dv = divs;
    const float* hp = h + (size_t)m * DIM;
    unsigned short* yp = hf + (size_t)m * DIM;
    #pragma unroll
    for (int seg = 0; seg < 3; ++seg) {
        int d0 = tid + seg * 256;
        yp[d0] = bc(hp[d0] + dv * ew[d0] + eb[d0]);
    }
}

// S16[b][x][dy][oc][i] (bf16) = sum over dx,j of ax(x+dx-1,j)*P[b][dy*3+dx][oc][i*16+j]
__global__ __launch_bounds__(256) void s_kernel(const float* __restrict__ P,
                                               unsigned short* __restrict__ S16)
{
    int bdy = blockIdx.y;
    int b = bdy / 3, dy = bdy % 3;
    int ocg = blockIdx.x;
    __shared__ float Pl[3][4][16][17];
    int tid = threadIdx.x;
    #pragma unroll
    for (int l = 0; l < 12; ++l) {
        int e = l * 256 + tid;
        int dx = e >> 10, rem = e & 1023;
        int oc = rem >> 8, pix = rem & 255;
        int i = pix >> 4, j = pix & 15;
        Pl[dx][oc][j][i] =
            P[(((size_t)b * 9 + dy * 3 + dx) * 256 + ocg * 4 + oc) * 256 + pix];
    }
    __syncthreads();
    int xq = tid >> 6, oc = (tid >> 4) & 3, i = tid & 15;
    for (int xx = 0; xx < 64; ++xx) {
        int x = xq * 64 + xx;
        float acc = 0.f;
        #pragma unroll
        for (int dx = 0; dx < 3; ++dx) {
            int u = x + dx - 1;
            float p = (u + 0.5f) * 0.0625f - 0.5f;
            float fl = floorf(p);
            float f = p - fl;
            int j0 = (int)fl;
            int ja = j0 < 0 ? 0 : j0;
            int jb = (j0 + 1 > 15) ? 15 : (j0 + 1);
            bool valid = (u >= 0) && (u <= 255);
            float w0 = valid ? 1.f - f : 0.f;
            float w1 = valid ? f : 0.f;
            acc += w0 * Pl[dx][oc][ja][i] + w1 * Pl[dx][oc][jb][i];
        }
        S16[(((size_t)(b * 256 + x) * 3 + dy) * 256 + ocg * 4 + oc) * 16 + i] = bc(acc);
    }
}

// out[b][y][x]; S16 slab per (b,x): [dy][oc][i] = 12288 bf16, expanded to fp32 LDS
__global__ __launch_bounds__(256) void out_kernel(
    const unsigned short* __restrict__ S16, const float* __restrict__ b1,
    const float* __restrict__ w2, const float* __restrict__ b2p,
    float* __restrict__ out)
{
    int b = blockIdx.x >> 8, x = blockIdx.x & 255;
    __shared__ float Sl[12288];
    const unsigned short* Sp = S16 + (size_t)(b * 256 + x) * 12288;
    #pragma unroll
    for (int c = 0; c < 6; ++c) {
        int l8 = (c * 256 + threadIdx.x) * 8;
        u16x8 v = *(const u16x8*)(Sp + l8);
        #pragma unroll
        for (int j = 0; j < 8; ++j) Sl[l8 + j] = fbc(v[j]);
    }
    __syncthreads();
    int y = threadIdx.x;
    float wy[3][2];
    int iy[3][2];
    #pragma unroll
    for (int dy = 0; dy < 3; ++dy) {
        int v = y + dy - 1;
        if (v < 0 || v > 255) {
            wy[dy][0] = wy[dy][1] = 0.f;
            iy[dy][0] = iy[dy][1] = 0;
        } else {
            float pp = (v + 0.5f) * 0.0625f - 0.5f;
            float fl = floorf(pp);
            float f = pp - fl;
            int i0 = (int)fl;
            iy[dy][0] = i0 < 0 ? 0 : i0;
            iy[dy][1] = (i0 + 1 > 15) ? 15 : (i0 + 1);
            wy[dy][0] = 1.f - f;
            wy[dy][1] = f;
        }
    }
    float acc = 0.f;
    for (int oc = 0; oc < 256; ++oc) {
        float sv = 0.f;
        #pragma unroll
        for (int dy = 0; dy < 3; ++dy)
            sv += wy[dy][0] * Sl[dy * 4096 + oc * 16 + iy[dy][0]]
                + wy[dy][1] * Sl[dy * 4096 + oc * 16 + iy[dy][1]];
        sv += b1[oc];
        acc += fmaxf(sv, 0.f) * w2[oc];
    }
    out[(size_t)b * 65536 + y * 256 + x] = acc + b2p[0];
}

extern "C" void kernel_launch(void* const* d_in, const int* in_sizes, int n_in,
                              void* d_out, int out_size, void* d_ws, size_t ws_size,
                              hipStream_t stream)
{
    const float* x         = (const float*)d_in[0];
    const float* patch_w   = (const float*)d_in[1];
    const float* patch_b   = (const float*)d_in[2];
    const float* pos_embed = (const float*)d_in[3];
    const float* in_proj_w = (const float*)d_in[4];
    const float* in_proj_b = (const float*)d_in[5];
    const float* out_w     = (const float*)d_in[6];
    const float* out_b     = (const float*)d_in[7];
    const float* ln1_g     = (const float*)d_in[8];
    const float* ln1_b     = (const float*)d_in[9];
    const float* ln2_g     = (const float*)d_in[10];
    const float* ln2_b     = (const float*)d_in[11];
    const float* ffn_w1    = (const float*)d_in[12];
    const float* ffn_b1    = (const float*)d_in[13];
    const float* ffn_w2    = (const float*)d_in[14];
    const float* ffn_b2    = (const float*)d_in[15];
    const float* edge_w    = (const float*)d_in[16];
    const float* edge_b    = (const float*)d_in[17];
    const float* conv1_w   = (const float*)d_in[18];
    const float* conv1_b   = (const float*)d_in[19];
    const float* conv2_w   = (const float*)d_in[20];
    const float* conv2_b   = (const float*)d_in[21];
    float* out = (float*)d_out;
    float* ws = (float*)d_ws;

    float* h      = ws;                        // 393216
    float* qkv    = h + 393216;                // 1179648
    float* orow   = qkv + 1179648;             // 393216
    float* ocol   = orow + 393216;             // 393216
    float* Pb     = ocol + 393216;             // 1179648
    float* amh    = Pb + 1179648;              // 98304
    float2* pstat = (float2*)(amh + 98304);    // 512*48 float2 = 49152 floats
    unsigned short* Sb16   = (unsigned short*)(amh + 98304 + 49152);   // 6291456
    unsigned short* hid16  = Sb16 + 6291456;                           // 1048576
    unsigned short* hfin16 = hid16 + 1048576;                          // 393216
    unsigned short* Wct16  = hfin16 + 393216;                          // 1769472

    wct_kernel<<<dim3(256), 256, 0, stream>>>(conv1_w, Wct16);

    // patch embed: A = x via im2col (fp32), B = patch_w (fp32, reg-staged);
    // writes pstat partials for LN1 of layer 0
    gemm_bf16<MB | MPOS | MAIM2 | MBF32 | MSTATP, 32><<<dim3(24 * 16), 256, 0, stream>>>(
        x, nullptr, patch_w, patch_b, pos_embed, nullptr, nullptr, nullptr, pstat,
        h, nullptr, 512, 768, 768, 1, 0, 0, 0, 0);

    for (int l = 0; l < NL; ++l) {
        gemm_bf16<MB | MLNA | MBF32, 64><<<dim3(36 * 16), 256, 0, stream>>>(
            h, nullptr, in_proj_w + (size_t)l * 1769472,
            in_proj_b + (size_t)l * 2304, nullptr,
            pstat, ln1_g + l * DIM, ln1_b + l * DIM, nullptr, qkv, nullptr,
            512, 2304, 768, 1, 0, 0, 0, 0);
        attn_kernel<<<dim3(BB * GG, 2, NH), 256, 0, stream>>>(
            qkv, orow, ocol, amh + (size_t)l * 12288);
        gemm_bf16<MB2 | MRES | MAS2 | MBF32 | MSTATP, 32><<<dim3(24 * 16), 256, 0, stream>>>(
            orow, ocol, out_w + (size_t)l * 589824,
            out_b + (size_t)l * DIM, nullptr,
            nullptr, nullptr, nullptr, pstat, h, nullptr,
            512, 768, 768, 1, 0, 0, 0, 0);
        gemm_bf16<MB | MRELU | MOBF16 | MLNA | MBF32, 64><<<dim3(32 * 16), 256, 0, stream>>>(
            h, nullptr, ffn_w1 + (size_t)l * 1572864,
            ffn_b1 + (size_t)l * FFD, nullptr,
            pstat, ln2_g + l * DIM, ln2_b + l * DIM, nullptr, nullptr, hid16,
            512, 2048, 768, 1, 0, 0, 0, 0);
        gemm_bf16<MB | MRES | MBF32 | MSTATP, 32><<<dim3(24 * 16), 256, 0, stream>>>(
            hid16, nullptr, ffn_w2 + (size_t)l * 1572864,
            ffn_b2 + (size_t)l * DIM, nullptr,
            nullptr, nullptr, nullptr, pstat, h, nullptr,
            512, 768, 2048, 1, 0, 0, 0, 0);
    }

    hfin_kernel<<<dim3(512), 256, 0, stream>>>(h, amh, edge_w, edge_b, hfin16);
    // P[b][dydx][oc][n]: z = dydx*2 + b, grid (8*8, 18) — both operands bf16
    gemm_bf16<0, 32><<<dim3(8 * 8, 18), 256, 0, stream>>>(
        Wct16, nullptr, hfin16, nullptr, nullptr, nullptr, nullptr, nullptr, nullptr,
        Pb, nullptr, 256, 256, 768,
        2, 196608LL, 196608LL, 65536LL, 589824LL);
    s_kernel<<<dim3(64, 6), 256, 0, stream>>>(Pb, Sb16);
    out_kernel<<<dim3(512), 256, 0, stream>>>(Sb16, conv1_b, conv2_w, conv2_b, out);
}